// Round 1
// 546.247 us; speedup vs baseline: 3.2202x; 3.2202x over previous
//
#include <hip/hip_runtime.h>
#include <math.h>

// B=32, R=16384, C=16, IC=16, OC=16, 3 routing iterations.
// x: (B,C,IC) fp32 [8192]; W: (R,C,OC,IC) fp32 [67108864 = 256 MB]; out: (B,C,OC) fp32.

#define RT 16384

typedef const __attribute__((address_space(1))) void GV;
typedef __attribute__((address_space(3))) void LV;

__device__ __forceinline__ float rfl(float v) {
    return __int_as_float(__builtin_amdgcn_readfirstlane(__float_as_int(v)));
}

// ---------------------------------------------------------------------------
// K1: wsum[c,o,i] = sum_r W[r,c,o,i].  W = 16,777,216 float4s.
// ---------------------------------------------------------------------------
__global__ __launch_bounds__(256) void k_wsum(const float4* __restrict__ W4,
                                              float* __restrict__ wsum) {
    int gid = blockIdx.x * 256 + threadIdx.x;      // [0, 262144)
    float4 acc = {0.f, 0.f, 0.f, 0.f};
    int idx = gid;
    #pragma unroll
    for (int it = 0; it < 64; ++it) {              // 16777216 / 262144 = 64
        float4 w = W4[idx];
        acc.x += w.x; acc.y += w.y; acc.z += w.z; acc.w += w.w;
        idx += 262144;
    }
    int cls = gid & 1023;                          // (c,o,i4) within an r-block
    atomicAdd(&wsum[cls * 4 + 0], acc.x);
    atomicAdd(&wsum[cls * 4 + 1], acc.y);
    atomicAdd(&wsum[cls * 4 + 2], acc.z);
    atomicAdd(&wsum[cls * 4 + 3], acc.w);
}

// ---------------------------------------------------------------------------
// K2: s1 = (1/R) * wsum . x ;  v1 = squash(s1)  -> v1[b*256 + c*16 + o]
// ---------------------------------------------------------------------------
__global__ __launch_bounds__(256) void k_v1(const float* __restrict__ wsum,
                                            const float* __restrict__ x,
                                            float* __restrict__ v1) {
    int t = blockIdx.x * 256 + threadIdx.x;        // 0..8191
    int o = t & 15, c = (t >> 4) & 15, b = t >> 8;
    const float* xb = x + (b * 16 + c) * 16;
    const float* wr = wsum + (c * 16 + o) * 16;
    float s = 0.f;
    #pragma unroll
    for (int i = 0; i < 16; ++i) s += wr[i] * xb[i];
    s *= (1.0f / 16384.0f);
    float ns = s * s;
    #pragma unroll
    for (int d = 1; d < 16; d <<= 1) ns += __shfl_xor(ns, d);
    v1[t] = s * (sqrtf(ns) / (1.0f + ns));
}

// ---------------------------------------------------------------------------
// K4: s = E/Z, v = squash(s) -> dst (v2 buffer or final out)
// ---------------------------------------------------------------------------
__global__ __launch_bounds__(256) void k_vout(const float* __restrict__ E,
                                              const float* __restrict__ Z,
                                              float* __restrict__ dst) {
    int t = blockIdx.x * 256 + threadIdx.x;        // 0..8191
    float s = E[t] / Z[t >> 4];                    // t>>4 = b*16+c
    float ns = s * s;
    #pragma unroll
    for (int d = 1; d < 16; d <<= 1) ns += __shfl_xor(ns, d);
    dst[t] = s * (sqrtf(ns) / (1.0f + ns));
}

// ---------------------------------------------------------------------------
// K3: fused routing pass.  For each (b,c,r):
//   u[o]  = sum_i W[r,c,o,i] * x[b,c,i]
//   L     = sum_o u[o] * v[b,c,o]  (+ Lprev if PASS3)
//   e     = exp(L) ; E[b,c,o] += e*u[o] ; Z[b,c] += e
//
// Spill-free version:
//   - x in SGPRs (readfirstlane; wave-uniform), v in 2 KB LDS block
//   - waves_per_eu(2,2): 1 block/CU, full 256-VGPR budget -> u[64]+accE[64] fit
//   - 128 KB double-buffered LDS; global_load_lds width-16 async staging with
//     the XOR swizzle applied to the GLOBAL source address (linear LDS dest)
//   - read swizzle folded to (lane*65) ^ m  (one v_xor per ds_read_b128)
// ---------------------------------------------------------------------------
template <int PASS3>
__global__ __launch_bounds__(512)
__attribute__((amdgpu_waves_per_eu(2, 2)))
void k_iter(const float* __restrict__ W,
            const float* __restrict__ x,
            const float* __restrict__ v,
            float* __restrict__ L,
            float* __restrict__ E,
            float* __restrict__ Z) {
    __shared__ float4 Wl[2][64 * 64];              // 128 KB: 2 x (64 rows x 1 KB)
    __shared__ float4 Vl[128];                     // v[b][o] for this c (2 KB)

    int c = blockIdx.y;
    int r0 = blockIdx.x * 256;
    int tid = threadIdx.x, wv = tid >> 6, lane = tid & 63;

    if (tid < 128) {                               // stage v block: Vl[b*4+j]
        int b = tid >> 2, j = tid & 3;
        Vl[tid] = ((const float4*)(v + (b * 16 + c) * 16))[j];
    }

    // x rows for this wave's 4 b's -> SGPRs (wave-uniform)
    float xs[4][16];
    #pragma unroll
    for (int bl = 0; bl < 4; ++bl) {
        const float4* xb = (const float4*)(x + ((wv * 4 + bl) * 16 + c) * 16);
        #pragma unroll
        for (int j = 0; j < 4; ++j) {
            float4 xv = xb[j];
            xs[bl][j * 4 + 0] = rfl(xv.x);
            xs[bl][j * 4 + 1] = rfl(xv.y);
            xs[bl][j * 4 + 2] = rfl(xv.z);
            xs[bl][j * 4 + 3] = rfl(xv.w);
        }
    }

    float accE[4][16];
    float accZ[4] = {0.f, 0.f, 0.f, 0.f};
    #pragma unroll
    for (int bl = 0; bl < 4; ++bl)
        #pragma unroll
        for (int o = 0; o < 16; ++o) accE[bl][o] = 0.f;

    const float4* W4c = (const float4*)W + (size_t)c * 64;   // row r at +r*1024

    // prologue: stage chunk 0 -> buf 0 (linear LDS dest, pre-swizzled source)
    #pragma unroll
    for (int k = 0; k < 8; ++k) {
        int row = k * 8 + wv;                                // wave-uniform
        const float4* src = W4c + (size_t)(r0 + row) * 1024 + (lane ^ row);
        __builtin_amdgcn_global_load_lds((GV*)src, (LV*)&Wl[0][row * 64], 16, 0, 0);
    }
    __syncthreads();

    int lane65 = lane * 65;                        // lane*64 + lane (disjoint bits)

    #pragma unroll
    for (int chunk = 0; chunk < 4; ++chunk) {
        int buf = chunk & 1;

        // prefetch next chunk into the other buffer (in flight during compute)
        if (chunk < 3) {
            int rb = r0 + (chunk + 1) * 64;
            #pragma unroll
            for (int k = 0; k < 8; ++k) {
                int row = k * 8 + wv;
                const float4* src = W4c + (size_t)(rb + row) * 1024 + (lane ^ row);
                __builtin_amdgcn_global_load_lds((GV*)src, (LV*)&Wl[buf ^ 1][row * 64],
                                                 16, 0, 0);
            }
        }

        const float4* Wlb = &Wl[buf][0];
        float u[4][16];
        #pragma unroll
        for (int o = 0; o < 16; ++o) {
            float4 w0 = Wlb[lane65 ^ (o * 4 + 0)];
            float4 w1 = Wlb[lane65 ^ (o * 4 + 1)];
            float4 w2 = Wlb[lane65 ^ (o * 4 + 2)];
            float4 w3 = Wlb[lane65 ^ (o * 4 + 3)];
            #pragma unroll
            for (int bl = 0; bl < 4; ++bl) {
                u[bl][o] =
                    w0.x*xs[bl][0]  + w0.y*xs[bl][1]  + w0.z*xs[bl][2]  + w0.w*xs[bl][3]  +
                    w1.x*xs[bl][4]  + w1.y*xs[bl][5]  + w1.z*xs[bl][6]  + w1.w*xs[bl][7]  +
                    w2.x*xs[bl][8]  + w2.y*xs[bl][9]  + w2.z*xs[bl][10] + w2.w*xs[bl][11] +
                    w3.x*xs[bl][12] + w3.y*xs[bl][13] + w3.z*xs[bl][14] + w3.w*xs[bl][15];
            }
        }

        int r = r0 + chunk * 64 + lane;
        #pragma unroll
        for (int bl = 0; bl < 4; ++bl) {
            int bc = (wv * 4 + bl) * 16 + c;
            float4 v0 = Vl[(wv * 4 + bl) * 4 + 0];
            float4 v1 = Vl[(wv * 4 + bl) * 4 + 1];
            float4 v2 = Vl[(wv * 4 + bl) * 4 + 2];
            float4 v3 = Vl[(wv * 4 + bl) * 4 + 3];
            float Lv =
                u[bl][0] *v0.x + u[bl][1] *v0.y + u[bl][2] *v0.z + u[bl][3] *v0.w +
                u[bl][4] *v1.x + u[bl][5] *v1.y + u[bl][6] *v1.z + u[bl][7] *v1.w +
                u[bl][8] *v2.x + u[bl][9] *v2.y + u[bl][10]*v2.z + u[bl][11]*v2.w +
                u[bl][12]*v3.x + u[bl][13]*v3.y + u[bl][14]*v3.z + u[bl][15]*v3.w;
            size_t li = (size_t)bc * RT + r;
            if (PASS3) Lv += L[li];
            else       L[li] = Lv;
            float e = __expf(Lv);
            accZ[bl] += e;
            #pragma unroll
            for (int o = 0; o < 16; ++o) accE[bl][o] += e * u[bl][o];
        }
        __syncthreads();
    }

    // Butterfly-reduce the 64 accE values + 4 accZ over the 64 lanes.
    float va = 0.f;
    #pragma unroll
    for (int bl = 0; bl < 4; ++bl) {
        #pragma unroll
        for (int o = 0; o < 16; ++o) {
            float t = accE[bl][o];
            #pragma unroll
            for (int d = 1; d < 64; d <<= 1) t += __shfl_xor(t, d);
            if (lane == bl * 16 + o) va = t;
        }
    }
    float vz = 0.f;
    #pragma unroll
    for (int bl = 0; bl < 4; ++bl) {
        float t = accZ[bl];
        #pragma unroll
        for (int d = 1; d < 64; d <<= 1) t += __shfl_xor(t, d);
        if (lane == bl) vz = t;
    }
    int b = wv * 4 + (lane >> 4);
    atomicAdd(&E[b * 256 + c * 16 + (lane & 15)], va);
    if (lane < 4) atomicAdd(&Z[(wv * 4 + lane) * 16 + c], vz);
}

// ---------------------------------------------------------------------------
// launch
// ---------------------------------------------------------------------------
extern "C" void kernel_launch(void* const* d_in, const int* in_sizes, int n_in,
                              void* d_out, int out_size, void* d_ws, size_t ws_size,
                              hipStream_t stream) {
    const float* x = (const float*)d_in[0];        // 8192 floats
    const float* W = (const float*)d_in[1];        // 67108864 floats (256 MB)
    float* out = (float*)d_out;                    // 8192 floats
    float* ws = (float*)d_ws;

    float* wsum = ws + 0;          // 4096
    float* E2   = ws + 4096;       // 8192
    float* Z2   = ws + 12288;      // 512
    float* E3   = ws + 12800;      // 8192
    float* Z3   = ws + 20992;      // 512   (accumulated region ends at 21504)
    float* v1   = ws + 21504;      // 8192
    float* v2   = ws + 29696;      // 8192
    float* L    = ws + 37888;      // 8388608 (33.5 MB)

    hipMemsetAsync(ws, 0, 21504 * sizeof(float), stream);

    // iter 1: uniform softmax -> v1 from Wsum (W pass 1)
    k_wsum<<<1024, 256, 0, stream>>>((const float4*)W, wsum);
    k_v1<<<32, 256, 0, stream>>>(wsum, x, v1);

    // iter 2 fused: L2 = <u, v1>, E2/Z2 accumulated in-pass (W pass 2)
    k_iter<0><<<dim3(64, 16), 512, 0, stream>>>(W, x, v1, L, E2, Z2);
    k_vout<<<32, 256, 0, stream>>>(E2, Z2, v2);    // v2 = squash(E2/Z2)

    // iter 3 fused: L3 = L2 + <u, v2>, E3/Z3 accumulated (W pass 3)
    k_iter<1><<<dim3(64, 16), 512, 0, stream>>>(W, x, v2, L, E3, Z3);
    k_vout<<<32, 256, 0, stream>>>(E3, Z3, out);   // out = squash(E3/Z3)
}